// Round 1
// baseline (441.224 us; speedup 1.0000x reference)
//
#include <hip/hip_runtime.h>
#include <hip/hip_bf16.h>

#define M_NODES 50000
#define K_DIM   512
#define N_DIM   128
#define N_EDGES_TOTAL 800000

// ---------------- GEMM: support = X @ W  (fp32, VALU) ----------------
// BM=64 rows, BN=128 (full D_OUT), BK=32. 256 threads, 8x4 acc per thread.
#define BM 64
#define BK 32
#define APAD 4   // pad to keep 16B alignment (68*4 % 16 == 0) and break bank conflicts

__global__ __launch_bounds__(256) void gemm_xw(const float* __restrict__ X,
                                               const float* __restrict__ W,
                                               float* __restrict__ S) {
  __shared__ float As[BK][BM + APAD];   // k-major: As[k][row]
  __shared__ float Bs[BK][N_DIM];       // Bs[k][col]

  const int tid = threadIdx.x;
  const int block_row = blockIdx.x * BM;
  const int tm = tid >> 5;   // 0..7  -> rows tm*8 .. tm*8+7
  const int tn = tid & 31;   // 0..31 -> cols tn*4 .. tn*4+3

  float acc[8][4];
#pragma unroll
  for (int i = 0; i < 8; ++i)
#pragma unroll
    for (int j = 0; j < 4; ++j) acc[i][j] = 0.f;

  for (int kk = 0; kk < K_DIM; kk += BK) {
    // A tile: 64 rows x 32 k = 512 float4, 2 per thread (transposed store)
#pragma unroll
    for (int l = 0; l < 2; ++l) {
      int idx = tid + l * 256;        // float4 index 0..511
      int row = idx >> 3;             // 8 float4 per row
      int c4  = idx & 7;
      float4 v = make_float4(0.f, 0.f, 0.f, 0.f);
      int grow = block_row + row;
      if (grow < M_NODES)
        v = *reinterpret_cast<const float4*>(&X[(size_t)grow * K_DIM + kk + c4 * 4]);
      As[c4 * 4 + 0][row] = v.x;
      As[c4 * 4 + 1][row] = v.y;
      As[c4 * 4 + 2][row] = v.z;
      As[c4 * 4 + 3][row] = v.w;
    }
    // B tile: 32 k x 128 cols = 1024 float4, 4 per thread
#pragma unroll
    for (int l = 0; l < 4; ++l) {
      int idx = tid + l * 256;        // float4 index; 32 per k-row
      int row = idx >> 5;
      int c4  = idx & 31;
      *reinterpret_cast<float4*>(&Bs[row][c4 * 4]) =
          *reinterpret_cast<const float4*>(&W[(size_t)(kk + row) * N_DIM + c4 * 4]);
    }
    __syncthreads();

#pragma unroll
    for (int k = 0; k < BK; ++k) {
      float4 a0 = *reinterpret_cast<const float4*>(&As[k][tm * 8]);
      float4 a1 = *reinterpret_cast<const float4*>(&As[k][tm * 8 + 4]);
      float4 b  = *reinterpret_cast<const float4*>(&Bs[k][tn * 4]);
      float av[8] = {a0.x, a0.y, a0.z, a0.w, a1.x, a1.y, a1.z, a1.w};
      float bv[4] = {b.x, b.y, b.z, b.w};
#pragma unroll
      for (int i = 0; i < 8; ++i)
#pragma unroll
        for (int j = 0; j < 4; ++j)
          acc[i][j] += av[i] * bv[j];
    }
    __syncthreads();
  }

#pragma unroll
  for (int i = 0; i < 8; ++i) {
    int grow = block_row + tm * 8 + i;
    if (grow < M_NODES) {
      float4 v = make_float4(acc[i][0], acc[i][1], acc[i][2], acc[i][3]);
      *reinterpret_cast<float4*>(&S[(size_t)grow * N_DIM + tn * 4]) = v;
    }
  }
}

// ---------------- SpMM: out = A @ support via sorted-dst run accumulation ----
// Each block: EPB contiguous edges, 128 threads = 1 per column.
// dst sorted -> accumulate runs in register, atomicAdd at run boundaries.
#define EPB 512

__global__ __launch_bounds__(128) void spmm_edges(const float* __restrict__ S,
                                                  const int* __restrict__ esrc,
                                                  const int* __restrict__ edst,
                                                  const float* __restrict__ eval,
                                                  float* __restrict__ out,
                                                  int n_edges) {
  __shared__ int   s_src[EPB];
  __shared__ int   s_dst[EPB];
  __shared__ float s_val[EPB];

  const int e0 = blockIdx.x * EPB;
  const int ne = min(EPB, n_edges - e0);
  const int tid = threadIdx.x;

  for (int i = tid; i < ne; i += 128) {
    s_src[i] = esrc[e0 + i];
    s_dst[i] = edst[e0 + i];
    s_val[i] = eval[e0 + i];
  }
  __syncthreads();

  const int c = tid;            // output column
  float acc = 0.f;
  int cur = s_dst[0];

  for (int i = 0; i < ne; i += 8) {
    const int m = min(8, ne - i);
    float v[8];
#pragma unroll
    for (int j = 0; j < 8; ++j)
      if (j < m) v[j] = S[(size_t)s_src[i + j] * N_DIM + c];
#pragma unroll
    for (int j = 0; j < 8; ++j) {
      if (j < m) {
        int d = s_dst[i + j];
        if (d != cur) {
          atomicAdd(&out[(size_t)cur * N_DIM + c], acc);
          acc = 0.f;
          cur = d;
        }
        acc += s_val[i + j] * v[j];
      }
    }
  }
  atomicAdd(&out[(size_t)cur * N_DIM + c], acc);
}

// ---------------- launch ----------------
extern "C" void kernel_launch(void* const* d_in, const int* in_sizes, int n_in,
                              void* d_out, int out_size, void* d_ws, size_t ws_size,
                              hipStream_t stream) {
  const float* x        = (const float*)d_in[0];
  const int*   edge_src = (const int*)d_in[1];
  const int*   edge_dst = (const int*)d_in[2];
  const float* edge_val = (const float*)d_in[3];
  const float* weight   = (const float*)d_in[4];
  float*       out      = (float*)d_out;
  float*       support  = (float*)d_ws;   // 50000*128*4 = 25.6 MB

  const int n_edges = in_sizes[1];

  // zero the output (poisoned to 0xAA before every launch)
  hipMemsetAsync(d_out, 0, (size_t)out_size * sizeof(float), stream);

  // GEMM: support = X @ W
  {
    dim3 grid((M_NODES + BM - 1) / BM);
    dim3 block(256);
    gemm_xw<<<grid, block, 0, stream>>>(x, weight, support);
  }

  // SpMM: out = segment_sum(support[src] * val, dst)
  {
    dim3 grid((n_edges + EPB - 1) / EPB);
    dim3 block(128);
    spmm_edges<<<grid, block, 0, stream>>>(support, edge_src, edge_dst, edge_val,
                                           out, n_edges);
  }
}

// Round 2
// 271.100 us; speedup vs baseline: 1.6275x; 1.6275x over previous
//
#include <hip/hip_runtime.h>
#include <hip/hip_bf16.h>

#define M_NODES 50000
#define K_DIM   512
#define N_DIM   128

typedef short s16x8 __attribute__((ext_vector_type(8)));
typedef float f32x4 __attribute__((ext_vector_type(4)));

static __device__ __forceinline__ ushort f2bf(float f) {
  uint u = __float_as_uint(f);
  u += 0x7fff + ((u >> 16) & 1);   // RNE
  return (ushort)(u >> 16);
}

// ---------------- prep: Wt[col][k] = bf16(W[k][col]), Wt is [128][512] bf16 ----
__global__ __launch_bounds__(256) void prep_wt(const float* __restrict__ W,
                                               ushort* __restrict__ Wt) {
  int t = blockIdx.x * 256 + threadIdx.x;   // 0..16383
  int k  = t >> 5;                          // 0..511
  int c0 = (t & 31) * 4;                    // 0..124
  float4 v = *reinterpret_cast<const float4*>(&W[(size_t)k * N_DIM + c0]);
  Wt[(size_t)(c0 + 0) * K_DIM + k] = f2bf(v.x);
  Wt[(size_t)(c0 + 1) * K_DIM + k] = f2bf(v.y);
  Wt[(size_t)(c0 + 2) * K_DIM + k] = f2bf(v.z);
  Wt[(size_t)(c0 + 3) * K_DIM + k] = f2bf(v.w);
}

// ---------------- GEMM: S = X @ W via bf16 MFMA, no LDS, no barriers ----------
// Block = 256 thr = 4 waves; wave w owns rows r0 = bid*64 + w*16 .. +15, all 128 cols.
// MFMA 16x16x32 bf16: A[l&15][(l>>4)*8+j], B[(l>>4)*8+j][l&15], D[(l>>4)*4+r][l&15].
__global__ __launch_bounds__(256, 4) void gemm_mfma(const float* __restrict__ X,
                                                    const ushort* __restrict__ Wt,
                                                    float* __restrict__ S) {
  const int tid = threadIdx.x;
  const int wid = tid >> 6;
  const int l   = tid & 63;
  const int l15 = l & 15;
  const int lg  = l >> 4;          // 0..3
  const int r0  = blockIdx.x * 64 + wid * 16;

  const int  arow   = r0 + l15;
  const bool avalid = arow < M_NODES;
  const float* xp = X + (size_t)(avalid ? arow : (M_NODES - 1)) * K_DIM + lg * 8;

  f32x4 acc[8];
#pragma unroll
  for (int n = 0; n < 8; ++n) acc[n] = (f32x4){0.f, 0.f, 0.f, 0.f};

  const ushort* bp[8];
#pragma unroll
  for (int n = 0; n < 8; ++n)
    bp[n] = Wt + (size_t)(n * 16 + l15) * K_DIM + lg * 8;

#pragma unroll 4
  for (int ks = 0; ks < K_DIM / 32; ++ks) {
    const int k0 = ks * 32;
    float4 a0 = *reinterpret_cast<const float4*>(xp + k0);
    float4 a1 = *reinterpret_cast<const float4*>(xp + k0 + 4);
    if (!avalid) {
      a0 = make_float4(0.f, 0.f, 0.f, 0.f);
      a1 = make_float4(0.f, 0.f, 0.f, 0.f);
    }
    s16x8 a;
    a[0] = (short)f2bf(a0.x); a[1] = (short)f2bf(a0.y);
    a[2] = (short)f2bf(a0.z); a[3] = (short)f2bf(a0.w);
    a[4] = (short)f2bf(a1.x); a[5] = (short)f2bf(a1.y);
    a[6] = (short)f2bf(a1.z); a[7] = (short)f2bf(a1.w);
#pragma unroll
    for (int n = 0; n < 8; ++n) {
      s16x8 b = *reinterpret_cast<const s16x8*>(bp[n] + k0);
      acc[n] = __builtin_amdgcn_mfma_f32_16x16x32_bf16(a, b, acc[n], 0, 0, 0);
    }
  }

#pragma unroll
  for (int n = 0; n < 8; ++n) {
#pragma unroll
    for (int r = 0; r < 4; ++r) {
      int row = r0 + lg * 4 + r;
      if (row < M_NODES)
        S[(size_t)row * N_DIM + n * 16 + l15] = acc[n][r];
    }
  }
}

// ---------------- SpMM: out = segment_sum(S[src]*val, dst), dst sorted --------
// EPB=256 (800000/256 = 3125 blocks exactly), 128 thr = 1 per column.
// 16-deep load batches, software-pipelined (issue batch i+1 before processing i).
#define EPB 256
#define BATCH 16

__global__ __launch_bounds__(128) void spmm_edges(const float* __restrict__ S,
                                                  const int* __restrict__ esrc,
                                                  const int* __restrict__ edst,
                                                  const float* __restrict__ eval,
                                                  float* __restrict__ out) {
  __shared__ int   s_src[EPB];
  __shared__ int   s_dst[EPB];
  __shared__ float s_val[EPB];

  const int e0  = blockIdx.x * EPB;
  const int tid = threadIdx.x;

#pragma unroll
  for (int i = 0; i < EPB / 128; ++i) {
    int idx = tid + i * 128;
    s_src[idx] = esrc[e0 + idx];
    s_dst[idx] = edst[e0 + idx];
    s_val[idx] = eval[e0 + idx];
  }
  __syncthreads();

  const int c = tid;               // output column 0..127
  float acc = 0.f;
  int   cur = s_dst[0];

  float va[BATCH], vb[BATCH];

  // prologue: load batch 0 into va
#pragma unroll
  for (int j = 0; j < BATCH; ++j)
    va[j] = S[(size_t)((int)s_src[j] * N_DIM + c)];

#pragma unroll
  for (int b = 0; b < EPB / BATCH; ++b) {
    const bool even = (b & 1) == 0;
    // issue next batch's loads into the other buffer
    if (b + 1 < EPB / BATCH) {
      const int base = (b + 1) * BATCH;
#pragma unroll
      for (int j = 0; j < BATCH; ++j) {
        float v = S[(size_t)((int)s_src[base + j] * N_DIM + c)];
        if (even) vb[j] = v; else va[j] = v;
      }
    }
    // process current batch
    const int pbase = b * BATCH;
#pragma unroll
    for (int j = 0; j < BATCH; ++j) {
      int d = s_dst[pbase + j];
      if (d != cur) {                       // block-uniform branch
        atomicAdd(&out[(size_t)cur * N_DIM + c], acc);
        acc = 0.f;
        cur = d;
      }
      float v = even ? va[j] : vb[j];
      acc += s_val[pbase + j] * v;
    }
  }
  atomicAdd(&out[(size_t)cur * N_DIM + c], acc);
}

// ---------------- launch ----------------
extern "C" void kernel_launch(void* const* d_in, const int* in_sizes, int n_in,
                              void* d_out, int out_size, void* d_ws, size_t ws_size,
                              hipStream_t stream) {
  const float* x        = (const float*)d_in[0];
  const int*   edge_src = (const int*)d_in[1];
  const int*   edge_dst = (const int*)d_in[2];
  const float* edge_val = (const float*)d_in[3];
  const float* weight   = (const float*)d_in[4];
  float*       out      = (float*)d_out;

  float*  support = (float*)d_ws;                                   // 25.6 MB
  ushort* wt      = (ushort*)((char*)d_ws + (size_t)M_NODES * N_DIM * 4); // 128 KB

  const int n_edges = in_sizes[1];

  hipMemsetAsync(d_out, 0, (size_t)out_size * sizeof(float), stream);

  prep_wt<<<dim3(64), dim3(256), 0, stream>>>(weight, wt);

  gemm_mfma<<<dim3((M_NODES + 63) / 64), dim3(256), 0, stream>>>(x, wt, support);

  spmm_edges<<<dim3(n_edges / EPB), dim3(128), 0, stream>>>(support, edge_src,
                                                            edge_dst, edge_val, out);
}